// Round 1
// baseline (202.207 us; speedup 1.0000x reference)
//
#include <hip/hip_runtime.h>

#define DEV __device__ __forceinline__

#define BIG 1.0e30f  // sentinel > any input (inputs are uniform [0,1))

DEV void ce(float& a, float& b) {
    float lo = fminf(a, b);
    float hi = fmaxf(a, b);
    a = lo;
    b = hi;
}

// Batcher odd-even merge on v[LO .. LO+N) at stride R.
// Precondition (R==1): v[LO..LO+N/2) sorted, v[LO+N/2..LO+N) sorted. N power of 2.
template <int LO, int N, int R>
struct OEMerge {
    DEV static void run(float* v) {
        constexpr int M = R * 2;
        if constexpr (M < N) {
            OEMerge<LO, N, M>::run(v);
            OEMerge<LO + R, N, M>::run(v);
#pragma unroll
            for (int i = LO + R; i + R < LO + N; i += M) ce(v[i], v[i + R]);
        } else {
            ce(v[LO], v[LO + R]);
        }
    }
};

// Batcher odd-even mergesort of v[LO .. LO+N), N power of 2.
template <int LO, int N>
struct OESort {
    DEV static void run(float* v) {
        if constexpr (N > 1) {
            constexpr int M = N / 2;
            OESort<LO, M>::run(v);
            OESort<LO + M, M>::run(v);
            OEMerge<LO, N, 1>::run(v);
        }
    }
};

static constexpr int W = 512;
static constexpr int H = 512;
static constexpr int PLANE = H * W;

__global__ __launch_bounds__(256) void median7_hardtanh_kernel(
    const float* __restrict__ in, float* __restrict__ out, int total) {
    int tid = blockIdx.x * 256 + threadIdx.x;
    if (tid >= total) return;

    int x = tid & (W - 1);
    int y = (tid >> 9) & (H - 1);
    int p = tid >> 18;
    const float* img = in + (size_t)p * PLANE;

    // reflect-padded row offsets and column indices (pad = 3, mirror w/o edge repeat)
    int rows[7], cols[7];
#pragma unroll
    for (int d = 0; d < 7; ++d) {
        int t = y + d - 3;
        t = (t < 0) ? -t : t;
        t = (t > H - 1) ? 2 * (H - 1) - t : t;
        rows[d] = t << 9;
        int u = x + d - 3;
        u = (u < 0) ? -u : u;
        u = (u > W - 1) ? 2 * (W - 1) - u : u;
        cols[d] = u;
    }

    // load 7 columns of 7, pad each to 8 with BIG
    float c[7][8];
#pragma unroll
    for (int j = 0; j < 7; ++j) {
#pragma unroll
        for (int i = 0; i < 7; ++i) c[j][i] = img[rows[i] + cols[j]];
        c[j][7] = BIG;
    }

    // sort each padded column: 19 CE each (Batcher sort-8)
#pragma unroll
    for (int j = 0; j < 7; ++j) OESort<0, 8>::run(c[j]);

    // A = merge(c0,c1): sorted 16 (14 real + 2 BIG)
    float A[16];
#pragma unroll
    for (int i = 0; i < 8; ++i) { A[i] = c[0][i]; A[8 + i] = c[1][i]; }
    OEMerge<0, 16, 1>::run(A);

    // B = merge(c2,c3)
    float B[16];
#pragma unroll
    for (int i = 0; i < 8; ++i) { B[i] = c[2][i]; B[8 + i] = c[3][i]; }
    OEMerge<0, 16, 1>::run(B);

    // M = merge(A,B): sorted 32 (28 real + 4 BIG)
    float M[32];
#pragma unroll
    for (int i = 0; i < 16; ++i) { M[i] = A[i]; M[16 + i] = B[i]; }
    OEMerge<0, 32, 1>::run(M);

    // A2 = merge(c4,c5): sorted 16 (14 real + 2 BIG)
    float A2[16];
#pragma unroll
    for (int i = 0; i < 8; ++i) { A2[i] = c[4][i]; A2[8 + i] = c[5][i]; }
    OEMerge<0, 16, 1>::run(A2);

    // F = merge(A2, c6): sorted 32 (21 real + 11 BIG)
    float F[32];
#pragma unroll
    for (int i = 0; i < 16; ++i) F[i] = A2[i];
#pragma unroll
    for (int i = 0; i < 8; ++i) F[16 + i] = c[6][i];
#pragma unroll
    for (int i = 24; i < 32; ++i) F[i] = BIG;
    OEMerge<0, 32, 1>::run(F);

    // rank-24 (0-indexed) of union(M[0..27], F[0..20]) via the two-sorted-list
    // selection identity: min over i+j==25 of max(M[i-1], F[j-1]).
    // Valid i range: i >= 25-21 = 4 (j <= 21), i <= 25 (j >= 0).
    float med = M[24];  // i = 25, j = 0 term
#pragma unroll
    for (int i = 4; i < 25; ++i) med = fminf(med, fmaxf(M[i - 1], F[24 - i]));

    // Hardtanh(0, 1)
    out[tid] = fminf(fmaxf(med, 0.0f), 1.0f);
}

extern "C" void kernel_launch(void* const* d_in, const int* in_sizes, int n_in,
                              void* d_out, int out_size, void* d_ws, size_t ws_size,
                              hipStream_t stream) {
    const float* x = (const float*)d_in[0];
    float* out = (float*)d_out;
    int total = out_size;  // 8*3*512*512 = 6291456
    int blocks = (total + 255) / 256;
    median7_hardtanh_kernel<<<blocks, 256, 0, stream>>>(x, out, total);
}

// Round 2
// 154.206 us; speedup vs baseline: 1.3113x; 1.3113x over previous
//
#include <hip/hip_runtime.h>

#define DEV __device__ __forceinline__

DEV void ce(float& a, float& b) {
    float lo = fminf(a, b);
    float hi = fmaxf(a, b);
    a = lo;
    b = hi;
}

// General Batcher odd-even merge: a[M] sorted, b[N] sorted -> out[M+N] sorted.
// Classic split (not both odd): E = a_evens+b_evens, O = a_odds+b_odds,
//   interleave E0 O0 E1 O1..., fixup ce(out[2i+1], out[2i+2]).
// Both-odd split: E = a_evens+b_odds, O = a_odds+b_evens (equal sizes),
//   interleave, fixup ce(out[2i], out[2i+1]) (fusable as min/max pairs).
template <int M, int N>
struct Merge {
    DEV static void run(const float* a, const float* b, float* out) {
        if constexpr (M == 0) {
#pragma unroll
            for (int i = 0; i < N; ++i) out[i] = b[i];
        } else if constexpr (N == 0) {
#pragma unroll
            for (int i = 0; i < M; ++i) out[i] = a[i];
        } else if constexpr (M == 1 && N == 1) {
            float lo = fminf(a[0], b[0]);
            float hi = fmaxf(a[0], b[0]);
            out[0] = lo;
            out[1] = hi;
        } else if constexpr ((M & 1) && (N & 1)) {
            constexpr int AE = (M + 1) / 2, AO = M / 2;
            constexpr int BE = (N + 1) / 2, BO = N / 2;
            float ae[AE], ao[AO > 0 ? AO : 1], be[BE], bo[BO > 0 ? BO : 1];
#pragma unroll
            for (int i = 0; i < AE; ++i) ae[i] = a[2 * i];
#pragma unroll
            for (int i = 0; i < AO; ++i) ao[i] = a[2 * i + 1];
#pragma unroll
            for (int i = 0; i < BE; ++i) be[i] = b[2 * i];
#pragma unroll
            for (int i = 0; i < BO; ++i) bo[i] = b[2 * i + 1];
            constexpr int CE_ = AE + BO, CO_ = AO + BE;  // equal when both odd
            float E[CE_], O[CO_];
            Merge<AE, BO>::run(ae, bo, E);
            Merge<AO, BE>::run(ao, be, O);
#pragma unroll
            for (int i = 0; i < CE_; ++i) {
                out[2 * i] = fminf(E[i], O[i]);
                out[2 * i + 1] = fmaxf(E[i], O[i]);
            }
        } else {
            constexpr int AE = (M + 1) / 2, AO = M / 2;
            constexpr int BE = (N + 1) / 2, BO = N / 2;
            float ae[AE], ao[AO > 0 ? AO : 1], be[BE], bo[BO > 0 ? BO : 1];
#pragma unroll
            for (int i = 0; i < AE; ++i) ae[i] = a[2 * i];
#pragma unroll
            for (int i = 0; i < AO; ++i) ao[i] = a[2 * i + 1];
#pragma unroll
            for (int i = 0; i < BE; ++i) be[i] = b[2 * i];
#pragma unroll
            for (int i = 0; i < BO; ++i) bo[i] = b[2 * i + 1];
            constexpr int CE_ = AE + BE, CO_ = AO + BO;  // CE_ - CO_ in {0,1}
            float E[CE_], O[CO_ > 0 ? CO_ : 1];
            Merge<AE, BE>::run(ae, be, E);
            Merge<AO, BO>::run(ao, bo, O);
            out[0] = E[0];
#pragma unroll
            for (int i = 0; i < CO_; ++i) {
                if (i + 1 < CE_) {
                    out[2 * i + 1] = fminf(O[i], E[i + 1]);
                    out[2 * i + 2] = fmaxf(O[i], E[i + 1]);
                } else {
                    out[2 * i + 1] = O[i];
                }
            }
        }
    }
};

// Merge-sort via the general merge. Sort<7> costs 16 CE (optimal size).
template <int N>
struct Sort {
    DEV static void run(float* v) {
        if constexpr (N > 1) {
            constexpr int Hh = N / 2;
            Sort<Hh>::run(v);
            Sort<N - Hh>::run(v + Hh);
            float tmp[N];
            Merge<Hh, N - Hh>::run(v, v + Hh, tmp);
#pragma unroll
            for (int i = 0; i < N; ++i) v[i] = tmp[i];
        }
    }
};

// rank-24 (0-indexed) of union(Mm[0..27], F[0..20]):
// min over i+j==25 (i elems from Mm, j from F) of max(Mm[i-1], F[j-1]).
DEV float select_rank24(const float* Mm, const float* F) {
    float med = Mm[24];  // i = 25, j = 0
#pragma unroll
    for (int i = 4; i < 25; ++i) med = fminf(med, fmaxf(Mm[i - 1], F[24 - i]));
    return med;
}

static constexpr int W = 512;
static constexpr int H = 512;
static constexpr int PLANE = W * H;

// One block = one image row (512 px); each thread computes 2 adjacent pixels.
// Shared-middle decomposition: pixel0 = cols 0..6, pixel1 = cols 1..7.
// M = merge(c1..c4) and S = merge(c5,c6) are shared between the two pixels.
__global__ __launch_bounds__(256, 2) void median7_hardtanh_kernel(
    const float* __restrict__ in, float* __restrict__ out) {
    int r = blockIdx.x;      // global row: plane * 512 + y
    int y = r & (H - 1);
    int p = r >> 9;
    const float* img = in + (size_t)p * PLANE;
    int x0 = (int)threadIdx.x * 2;

    int rows[7];
#pragma unroll
    for (int i = 0; i < 7; ++i) {
        int t = y + i - 3;
        t = (t < 0) ? -t : t;
        t = (t > H - 1) ? 2 * (H - 1) - t : t;
        rows[i] = t << 9;
    }
    int cols[8];
#pragma unroll
    for (int j = 0; j < 8; ++j) {
        int u = x0 + j - 3;
        u = (u < 0) ? -u : u;
        u = (u > W - 1) ? 2 * (W - 1) - u : u;
        cols[j] = u;
    }

    // 8 columns of 7 (pixel0: cols 0..6, pixel1: cols 1..7)
    float c[8][7];
#pragma unroll
    for (int j = 0; j < 8; ++j) {
#pragma unroll
        for (int i = 0; i < 7; ++i) c[j][i] = img[rows[i] + cols[j]];
    }

#pragma unroll
    for (int j = 0; j < 8; ++j) Sort<7>::run(c[j]);

    // Shared middle: M = sorted 28 of columns 1..4
    float A[14], B[14], Mm[28];
    Merge<7, 7>::run(c[1], c[2], A);
    Merge<7, 7>::run(c[3], c[4], B);
    Merge<14, 14>::run(A, B, Mm);

    // Shared pair: S = sorted 14 of columns 5,6
    float S[14];
    Merge<7, 7>::run(c[5], c[6], S);

    // Pixel 0: F0 = merge(S, c0) -> sorted 21
    float F0[21];
    Merge<14, 7>::run(S, c[0], F0);
    float med0 = select_rank24(Mm, F0);

    // Pixel 1: F1 = merge(S, c7) -> sorted 21
    float F1[21];
    Merge<14, 7>::run(S, c[7], F1);
    float med1 = select_rank24(Mm, F1);

    float2 o;
    o.x = fminf(fmaxf(med0, 0.0f), 1.0f);
    o.y = fminf(fmaxf(med1, 0.0f), 1.0f);
    *reinterpret_cast<float2*>(out + (size_t)r * W + x0) = o;
}

extern "C" void kernel_launch(void* const* d_in, const int* in_sizes, int n_in,
                              void* d_out, int out_size, void* d_ws, size_t ws_size,
                              hipStream_t stream) {
    const float* x = (const float*)d_in[0];
    float* outp = (float*)d_out;
    int rows_total = out_size / W;  // 8*3*512 = 12288
    median7_hardtanh_kernel<<<rows_total, 256, 0, stream>>>(x, outp);
}

// Round 3
// 132.305 us; speedup vs baseline: 1.5283x; 1.1655x over previous
//
#include <hip/hip_runtime.h>

#define DEV __device__ __forceinline__

// Fixed-size value-semantics vector: everything passed/returned BY VALUE so
// that after inlining the whole network is pure SSA (no address-taken arrays,
// no scratch, no AGPR shuffling).
template <int N> struct V { float v[N == 0 ? 1 : N]; };

// General Batcher odd-even merge, by value. Logic identical to the round-2
// pointer version (verified absmax = 0.0), only the calling convention changed.
template <int M, int N>
DEV V<M + N> mrg(V<M> a, V<N> b) {
    V<M + N> o;
    if constexpr (M == 0) {
#pragma unroll
        for (int i = 0; i < N; ++i) o.v[i] = b.v[i];
    } else if constexpr (N == 0) {
#pragma unroll
        for (int i = 0; i < M; ++i) o.v[i] = a.v[i];
    } else if constexpr (M == 1 && N == 1) {
        o.v[0] = fminf(a.v[0], b.v[0]);
        o.v[1] = fmaxf(a.v[0], b.v[0]);
    } else if constexpr ((M & 1) && (N & 1)) {
        // both odd: E = a_even + b_odd, O = a_odd + b_even (equal sizes),
        // interleave as fused min/max pairs.
        constexpr int AE = (M + 1) / 2, AO = M / 2, BE = (N + 1) / 2, BO = N / 2;
        V<AE> ae; V<AO> ao; V<BE> be; V<BO> bo;
#pragma unroll
        for (int i = 0; i < AE; ++i) ae.v[i] = a.v[2 * i];
#pragma unroll
        for (int i = 0; i < AO; ++i) ao.v[i] = a.v[2 * i + 1];
#pragma unroll
        for (int i = 0; i < BE; ++i) be.v[i] = b.v[2 * i];
#pragma unroll
        for (int i = 0; i < BO; ++i) bo.v[i] = b.v[2 * i + 1];
        V<AE + BO> E = mrg<AE, BO>(ae, bo);
        V<AO + BE> O = mrg<AO, BE>(ao, be);
        constexpr int P = AE + BO;  // == AO + BE
#pragma unroll
        for (int i = 0; i < P; ++i) {
            o.v[2 * i] = fminf(E.v[i], O.v[i]);
            o.v[2 * i + 1] = fmaxf(E.v[i], O.v[i]);
        }
    } else {
        // classic split: E = evens, O = odds; out = E0 [O_i,E_{i+1}] ...
        constexpr int AE = (M + 1) / 2, AO = M / 2, BE = (N + 1) / 2, BO = N / 2;
        V<AE> ae; V<AO> ao; V<BE> be; V<BO> bo;
#pragma unroll
        for (int i = 0; i < AE; ++i) ae.v[i] = a.v[2 * i];
#pragma unroll
        for (int i = 0; i < AO; ++i) ao.v[i] = a.v[2 * i + 1];
#pragma unroll
        for (int i = 0; i < BE; ++i) be.v[i] = b.v[2 * i];
#pragma unroll
        for (int i = 0; i < BO; ++i) bo.v[i] = b.v[2 * i + 1];
        V<AE + BE> E = mrg<AE, BE>(ae, be);
        V<AO + BO> O = mrg<AO, BO>(ao, bo);
        constexpr int CEn = AE + BE, COn = AO + BO;  // CEn - COn in {0,1}
        o.v[0] = E.v[0];
#pragma unroll
        for (int i = 0; i < COn; ++i) {
            if (i + 1 < CEn) {
                o.v[2 * i + 1] = fminf(O.v[i], E.v[i + 1]);
                o.v[2 * i + 2] = fmaxf(O.v[i], E.v[i + 1]);
            } else {
                o.v[2 * i + 1] = O.v[i];
            }
        }
    }
    return o;
}

DEV void ce(float& a, float& b) {
    float lo = fminf(a, b);
    b = fmaxf(a, b);
    a = lo;
}

// sort7 = sort3(x0..x2) + sort4(x3..x6) + merge(3,4); 3+5+8 = 16 CE.
DEV V<7> sort7(V<7> x) {
    ce(x.v[1], x.v[2]); ce(x.v[0], x.v[2]); ce(x.v[0], x.v[1]);
    ce(x.v[3], x.v[4]); ce(x.v[5], x.v[6]); ce(x.v[3], x.v[5]);
    ce(x.v[4], x.v[6]); ce(x.v[4], x.v[5]);
    V<3> a; a.v[0] = x.v[0]; a.v[1] = x.v[1]; a.v[2] = x.v[2];
    V<4> b; b.v[0] = x.v[3]; b.v[1] = x.v[4]; b.v[2] = x.v[5]; b.v[3] = x.v[6];
    return mrg<3, 4>(a, b);
}

// rank-24 (0-indexed) of union(Q[0..27], F[0..20]):
// min over i+j==25 of max(Q[i-1], F[j-1]); i in [4,25]. (verified absmax=0)
DEV float sel24(V<28> Q, V<21> F) {
    float m = Q.v[24];  // i = 25, j = 0
#pragma unroll
    for (int i = 4; i < 25; ++i) m = fminf(m, fmaxf(Q.v[i - 1], F.v[24 - i]));
    return m;
}

static constexpr int W = 512, H = 512, PLANE = W * H;

// Each thread computes 4 consecutive pixels (x0..x0+3), needing sorted columns
// c0..c9 (window cols x0-3..x0+6). Shared: Q = merge(c3..c6) (all 4 px),
// P12 = merge(c1,c2) (px0,px1), P78 = merge(c7,c8) (px2,px3).
//   px0 = Q + merge(P12, c0)   px1 = Q + merge(P12, c7)
//   px2 = Q + merge(P78, c2)   px3 = Q + merge(P78, c9)
__global__ __launch_bounds__(256, 1) void median7_hardtanh_kernel(
    const float* __restrict__ in, float* __restrict__ out) {
    int local = (int)threadIdx.x;
    int tx = local & 127;          // 128 threads per row
    int ry = local >> 7;           // 2 rows per block
    int r = blockIdx.x * 2 + ry;   // global row = plane*512 + y
    int y = r & (H - 1);
    int p = r >> 9;
    const float* img = in + (size_t)p * PLANE;
    int x0 = tx * 4;

    int rows[7];
#pragma unroll
    for (int i = 0; i < 7; ++i) {
        int t = y + i - 3;
        t = (t < 0) ? -t : t;
        t = (t > H - 1) ? 2 * (H - 1) - t : t;
        rows[i] = t << 9;
    }

    V<7> c0, c1, c2, c3, c4, c5, c6, c7, c8, c9;
    if (x0 >= 4 && x0 <= W - 8) {
        // interior: 3 aligned float4 loads per row cover cols x0-4 .. x0+7
#pragma unroll
        for (int i = 0; i < 7; ++i) {
            const float* rp = img + rows[i] + x0;
            float4 L = *reinterpret_cast<const float4*>(rp - 4);
            float4 C = *reinterpret_cast<const float4*>(rp);
            float4 R = *reinterpret_cast<const float4*>(rp + 4);
            c0.v[i] = L.y; c1.v[i] = L.z; c2.v[i] = L.w;
            c3.v[i] = C.x; c4.v[i] = C.y; c5.v[i] = C.z; c6.v[i] = C.w;
            c7.v[i] = R.x; c8.v[i] = R.y; c9.v[i] = R.z;
        }
    } else {
        int cols[10];
#pragma unroll
        for (int j = 0; j < 10; ++j) {
            int u = x0 + j - 3;
            u = (u < 0) ? -u : u;
            u = (u > W - 1) ? 2 * (W - 1) - u : u;
            cols[j] = u;
        }
#pragma unroll
        for (int i = 0; i < 7; ++i) {
            const float* rp = img + rows[i];
            c0.v[i] = rp[cols[0]]; c1.v[i] = rp[cols[1]]; c2.v[i] = rp[cols[2]];
            c3.v[i] = rp[cols[3]]; c4.v[i] = rp[cols[4]]; c5.v[i] = rp[cols[5]];
            c6.v[i] = rp[cols[6]]; c7.v[i] = rp[cols[7]]; c8.v[i] = rp[cols[8]];
            c9.v[i] = rp[cols[9]];
        }
    }

    c0 = sort7(c0); c1 = sort7(c1); c2 = sort7(c2); c3 = sort7(c3);
    c4 = sort7(c4); c5 = sort7(c5); c6 = sort7(c6); c7 = sort7(c7);
    c8 = sort7(c8); c9 = sort7(c9);

    V<28> Q = mrg<14, 14>(mrg<7, 7>(c3, c4), mrg<7, 7>(c5, c6));
    V<14> P12 = mrg<7, 7>(c1, c2);
    V<14> P78 = mrg<7, 7>(c7, c8);

    float m0 = sel24(Q, mrg<14, 7>(P12, c0));
    float m1 = sel24(Q, mrg<14, 7>(P12, c7));
    float m2 = sel24(Q, mrg<14, 7>(P78, c2));
    float m3 = sel24(Q, mrg<14, 7>(P78, c9));

    float4 o;
    o.x = fminf(fmaxf(m0, 0.0f), 1.0f);
    o.y = fminf(fmaxf(m1, 0.0f), 1.0f);
    o.z = fminf(fmaxf(m2, 0.0f), 1.0f);
    o.w = fminf(fmaxf(m3, 0.0f), 1.0f);
    *reinterpret_cast<float4*>(out + (size_t)r * W + x0) = o;
}

extern "C" void kernel_launch(void* const* d_in, const int* in_sizes, int n_in,
                              void* d_out, int out_size, void* d_ws, size_t ws_size,
                              hipStream_t stream) {
    const float* x = (const float*)d_in[0];
    float* outp = (float*)d_out;
    int rows_total = out_size / W;      // 12288
    int blocks = rows_total / 2;        // 6144 (2 rows per 256-thread block)
    median7_hardtanh_kernel<<<blocks, 256, 0, stream>>>(x, outp);
}